// Round 1
// baseline (194.305 us; speedup 1.0000x reference)
//
#include <hip/hip_runtime.h>

// TSM_6330781795061: output = input, except
//   channels [0,21)  zeroed where t == 0   (t = b % 180)
//   channels [21,42) zeroed where t == 179
// Shapes: input (1440, 64, 36, 36) fp32.  HW = 1296 = 324 float4s per plane.

constexpr unsigned kTime   = 180;
constexpr unsigned kFold   = 21;      // 64 / 3
constexpr unsigned kHW4    = 324;     // 36*36 / 4
constexpr unsigned kTotal4 = 1440u * 64u * kHW4;  // 29,859,840 float4 elements

__global__ void tsm_copy_kernel(const float4* __restrict__ in,
                                float4* __restrict__ out) {
    unsigned stride = gridDim.x * blockDim.x;
    for (unsigned i = blockIdx.x * blockDim.x + threadIdx.x; i < kTotal4;
         i += stride) {
        unsigned plane = i / kHW4;       // b*64 + c  (constant divisor -> magic mul)
        unsigned c = plane & 63u;
        unsigned b = plane >> 6;
        unsigned t = b % kTime;          // constant divisor -> magic mul
        bool zero = (t == 0u && c < kFold) ||
                    (t == kTime - 1u && c >= kFold && c < 2u * kFold);
        float4 v = in[i];
        if (zero) v = make_float4(0.f, 0.f, 0.f, 0.f);
        out[i] = v;
    }
}

extern "C" void kernel_launch(void* const* d_in, const int* in_sizes, int n_in,
                              void* d_out, int out_size, void* d_ws, size_t ws_size,
                              hipStream_t stream) {
    const float4* in = (const float4*)d_in[0];
    float4* out = (float4*)d_out;
    const int block = 256;
    const int grid = 2048;  // 256 CUs x 8 blocks/CU, grid-stride covers the rest
    tsm_copy_kernel<<<grid, block, 0, stream>>>(in, out);
}

// Round 2
// 185.287 us; speedup vs baseline: 1.0487x; 1.0487x over previous
//
#include <hip/hip_runtime.h>

// TSM_6330781795061: output = input, except
//   channels [0,21)  zeroed where t == 0   (t = b % 180)
//   channels [21,42) zeroed where t == 179
// Shapes: input (1440, 64, 36, 36) fp32.  HW = 1296 floats = 324 float4/plane.
//
// Pure streaming copy: 478 MB in + 478 MB out. Strategy: exact-trip-count
// mapping (1620 blocks x 256 thr x 72 float4/thread), unroll x8 with all 8
// loads issued before any store (MLP), non-temporal hints (no reuse).

typedef float f32x4 __attribute__((ext_vector_type(4)));

constexpr unsigned kTime     = 180;
constexpr unsigned kFold     = 21;                    // 64 / 3
constexpr unsigned kHW4      = 324;                   // 36*36 / 4
constexpr unsigned kTotal4   = 1440u * 64u * kHW4;    // 29,859,840
constexpr unsigned kBlocks   = 1620;
constexpr unsigned kThreads  = 256;
constexpr unsigned kStride   = kBlocks * kThreads;    // 414,720
constexpr unsigned kPerThr   = kTotal4 / kStride;     // 72 exactly (no tail)
constexpr unsigned kUnroll   = 8;

static_assert(kPerThr * kStride == kTotal4, "exact cover");
static_assert(kPerThr % kUnroll == 0, "no tail");

__global__ __launch_bounds__(kThreads)
void tsm_copy_kernel(const f32x4* __restrict__ in, f32x4* __restrict__ out) {
    const unsigned tid = blockIdx.x * kThreads + threadIdx.x;

    for (unsigned k = 0; k < kPerThr; k += kUnroll) {
        f32x4 v[kUnroll];
        unsigned idx[kUnroll];

        // Phase 1: issue all 8 independent loads (128 B/lane in flight).
#pragma unroll
        for (unsigned u = 0; u < kUnroll; ++u) {
            idx[u] = tid + (k + u) * kStride;
            v[u] = __builtin_nontemporal_load(&in[idx[u]]);
        }

        // Phase 2: predicate + store.
#pragma unroll
        for (unsigned u = 0; u < kUnroll; ++u) {
            unsigned plane = idx[u] / kHW4;   // b*64 + c (magic-mul div)
            unsigned c = plane & 63u;
            unsigned b = plane >> 6;
            unsigned t = b % kTime;           // magic-mul div
            bool zero = (t == 0u && c < kFold) ||
                        (t == kTime - 1u && c >= kFold && c < 2u * kFold);
            if (zero) v[u] = f32x4{0.f, 0.f, 0.f, 0.f};
            __builtin_nontemporal_store(v[u], &out[idx[u]]);
        }
    }
}

extern "C" void kernel_launch(void* const* d_in, const int* in_sizes, int n_in,
                              void* d_out, int out_size, void* d_ws, size_t ws_size,
                              hipStream_t stream) {
    const f32x4* in = (const f32x4*)d_in[0];
    f32x4* out = (f32x4*)d_out;
    tsm_copy_kernel<<<kBlocks, kThreads, 0, stream>>>(in, out);
}